// Round 3
// baseline (266.408 us; speedup 1.0000x reference)
//
#include <hip/hip_runtime.h>

// ---------------------------------------------------------------------------
// Fused NeRF MLP forward: 262144 rows, 63-in, 8x256 hidden + skip at L4->L5,
// 4-dim output. fp16 MFMA (16x16x32) with fp32 accumulation.
//
// R3: half-layer-staggered dual row-groups. Each block owns 64 rows split
// into two independent 32-row groups (A/B). Pipeline (one barrier per
// segment, two segments per layer):
//   segA(L): mainA(L)  || epiB(L-1)                      [no global loads]
//   segB(L): mainB(L)  || epiA(L)   || stream W(L+1)->w  [replace-after-use]
// Full layer weights live in registers w[8][4] (128 VGPR) so A and B share
// one load per fragment per block. Every segment has 64 MFMAs to hide the
// overlapped epilogue + loads -> no MFMA-free phases (R2's stall source).
// VGPR ~240 -> 2 waves/SIMD; per-wave MFMA duty ~85% -> pipe ~saturated.
// Fragment/prep layout, k-bijection, C layout identical to R2.
// ---------------------------------------------------------------------------

typedef _Float16 h8 __attribute__((ext_vector_type(8)));
typedef float f4 __attribute__((ext_vector_type(4)));

// fragment-linear weight offsets, in halves:
// L0 K=64, L1..L4 K=256, L5 K=320, L6,L7 K=256, OUT K=256 (NF=1, n padded to 16)
#define OFF_L0   0
#define OFF_L1   16384
#define OFF_L2   81920
#define OFF_L3   147456
#define OFF_L4   212992
#define OFF_L5   278528
#define OFF_L6   360448
#define OFF_L7   425984
#define OFF_OUT  491520
#define TOT_HALVES 495616
#define TOT_GROUPS (TOT_HALVES / 8)   // 61952

__global__ void nerf_prep(const float* __restrict__ W0, const float* __restrict__ W1,
                          const float* __restrict__ W2, const float* __restrict__ W3,
                          const float* __restrict__ W4, const float* __restrict__ W5,
                          const float* __restrict__ W6, const float* __restrict__ W7,
                          const float* __restrict__ Wout, _Float16* __restrict__ wf)
{
    int g = blockIdx.x * 256 + threadIdx.x;     // one 8-half fragment group
    if (g >= TOT_GROUPS) return;

    const int bounds[10] = {0, 2048, 10240, 18432, 26624, 34816, 45056, 53248, 61440, 61952};
    const float* Ws[9] = {W0, W1, W2, W3, W4, W5, W6, W7, Wout};

    int L = 0;
    while (L < 8 && g >= bounds[L + 1]) ++L;

    int t    = g - bounds[L];
    int lane = t & 63;
    int q    = t >> 6;
    int NF   = (L == 8) ? 1 : 16;
    int nf   = q % NF;
    int ks   = q / NF;
    int n    = nf * 16 + (lane & 15);
    int k0   = ks * 32 + (lane >> 4) * 8;

    const float* W = Ws[L];
    h8 v;
#pragma unroll
    for (int i = 0; i < 8; ++i) {
        int k = k0 + i;
        float val = 0.f;
        if (L == 0) {
            if (k < 63) val = W[k * 256 + n];                 // 63x256, pad k=63
        } else if (L == 5) {
            // k' < 256 -> h part (orig row 63+k'); k' >= 256 -> x part (orig row k'-256)
            if (k < 256)            val = W[(63 + k) * 256 + n];
            else if ((k - 256) < 63) val = W[(k - 256) * 256 + n];
        } else if (L == 8) {
            if (n < 4) val = W[k * 4 + n];                    // 256x4, pad n to 16
        } else {
            val = W[k * 256 + n];                             // 256x256
        }
        v[i] = (_Float16)val;
    }
    *(h8*)(wf + (size_t)g * 8) = v;
}

__device__ __forceinline__ const h8* bfrag_ptr(const _Float16* __restrict__ w,
                                               int ks, int wid, int nf, int lane)
{
    return (const h8*)(w + (size_t)((ks * 16 + (wid * 4 + nf)) * 64 + lane) * 8);
}

__device__ __forceinline__ const h8* ofrag_ptr(const _Float16* __restrict__ w,
                                               int ks, int lane)
{
    return (const h8*)(w + (size_t)(ks * 64 + lane) * 8);
}

// One pipeline segment, ends with __syncthreads().
//  WK:     ks-depth of the register weight file (8 normal, 2 for L0)
//  NSLOT:  main-loop ks steps (== WK consumed)
//  MODE:   0 = A-frags from hm, 1 = A-frags from xm (L0)
//  XTRA:   two extra ks steps from xm via wx (L5 skip-concat tail)
//  DO_EPI: overlap the other group's previous-layer epilogue (8 chunks)
//  DO_LOAD: replace w[j][*] after last use with next layer's fragments
//  WXMODE: 0 none, 1 load wx <- L5 x-part frags (ks 8,9), 2 load wx <- Wout
template <int WK, int NSLOT, int MODE, bool XTRA, bool DO_EPI, bool DO_LOAD, int WXMODE>
__device__ __forceinline__ void segment(
    const _Float16 (&hm)[32][264], const _Float16 (&xm)[32][72],
    _Float16 (&he)[32][264],
    h8 (&w)[WK][4], h8 (&wx)[2][4],
    const _Float16* __restrict__ wnext,
    const _Float16* __restrict__ wxsrc,
    f4 (&accM)[2][4], f4 (&accE)[2][4],
    const float (&bve)[4],
    int wid, int lane)
{
    const int lg = lane >> 4, ln = lane & 15;

    if constexpr (WXMODE == 1) {       // L5 x-part weights (consumed at XTRA slots)
#pragma unroll
        for (int s = 0; s < 2; ++s)
#pragma unroll
            for (int nf = 0; nf < 4; ++nf)
                wx[s][nf] = *bfrag_ptr(wxsrc, 8 + s, wid, nf, lane);
    } else if constexpr (WXMODE == 2) { // Wout (consumed by the out stage)
#pragma unroll
        for (int ks = 0; ks < 8; ++ks)
            wx[ks >> 2][ks & 3] = *ofrag_ptr(wxsrc, ks, lane);
    }

    // zero this group's accumulator (its previous epi ran last segment)
#pragma unroll
    for (int mf = 0; mf < 2; ++mf)
#pragma unroll
        for (int nf = 0; nf < 4; ++nf)
#pragma unroll
            for (int i = 0; i < 4; ++i) accM[mf][nf][i] = 0.f;

#pragma unroll
    for (int j = 0; j < NSLOT; ++j) {
        h8 afr0, afr1;
        if constexpr (MODE == 1) {
            afr0 = *(const h8*)&xm[ln][j * 32 + lg * 8];
            afr1 = *(const h8*)&xm[16 + ln][j * 32 + lg * 8];
        } else {
            afr0 = *(const h8*)&hm[ln][j * 32 + lg * 8];
            afr1 = *(const h8*)&hm[16 + ln][j * 32 + lg * 8];
        }
#pragma unroll
        for (int nf = 0; nf < 4; ++nf) {
            accM[0][nf] = __builtin_amdgcn_mfma_f32_16x16x32_f16(afr0, w[j][nf], accM[0][nf], 0, 0, 0);
            accM[1][nf] = __builtin_amdgcn_mfma_f32_16x16x32_f16(afr1, w[j][nf], accM[1][nf], 0, 0, 0);
        }
        if constexpr (DO_LOAD) {        // replace-after-last-use: stream next layer in
#pragma unroll
            for (int nf = 0; nf < 4; ++nf)
                w[j][nf] = *bfrag_ptr(wnext, j, wid, nf, lane);
        }
        if constexpr (DO_EPI) {
            if (j < 8) {                // compile-time after unroll
                const int mf_ = j & 1, nf_ = j >> 1;
                float b_ = bve[nf_];
#pragma unroll
                for (int i = 0; i < 4; ++i) {
                    float v_ = accE[mf_][nf_][i] + b_;
                    v_ = fmaxf(v_, 0.f);
                    // C layout (m89): row = (lane>>4)*4 + reg, col = lane&15
                    he[mf_ * 16 + lg * 4 + i][wid * 64 + nf_ * 16 + ln] = (_Float16)v_;
                }
            }
        }
    }
    if constexpr (XTRA) {               // L5 skip: 2 extra ks from x
#pragma unroll
        for (int s = 0; s < 2; ++s) {
            h8 afr0 = *(const h8*)&xm[ln][s * 32 + lg * 8];
            h8 afr1 = *(const h8*)&xm[16 + ln][s * 32 + lg * 8];
#pragma unroll
            for (int nf = 0; nf < 4; ++nf) {
                accM[0][nf] = __builtin_amdgcn_mfma_f32_16x16x32_f16(afr0, wx[s][nf], accM[0][nf], 0, 0, 0);
                accM[1][nf] = __builtin_amdgcn_mfma_f32_16x16x32_f16(afr1, wx[s][nf], accM[1][nf], 0, 0, 0);
            }
        }
    }
    if constexpr (DO_EPI && NSLOT < 8) { // short segments (L0): remaining chunks
#pragma unroll
        for (int j = NSLOT; j < 8; ++j) {
            const int mf_ = j & 1, nf_ = j >> 1;
            float b_ = bve[nf_];
#pragma unroll
            for (int i = 0; i < 4; ++i) {
                float v_ = accE[mf_][nf_][i] + b_;
                v_ = fmaxf(v_, 0.f);
                he[mf_ * 16 + lg * 4 + i][wid * 64 + nf_ * 16 + ln] = (_Float16)v_;
            }
        }
    }
    __syncthreads();
}

__global__ __launch_bounds__(256, 2) void nerf_fused(
    const float* __restrict__ x,
    const float* __restrict__ b0, const float* __restrict__ b1, const float* __restrict__ b2,
    const float* __restrict__ b3, const float* __restrict__ b4, const float* __restrict__ b5,
    const float* __restrict__ b6, const float* __restrict__ b7, const float* __restrict__ bout,
    const _Float16* __restrict__ wf,
    float* __restrict__ out)
{
    __shared__ _Float16 hb[2][32][264];   // per-group activations (pad 8 halves)
    __shared__ _Float16 xb[2][32][72];    // per-group x (63 real + pad)

    const int tid  = threadIdx.x;
    const int wid  = tid >> 6;
    const int lane = tid & 63;
    const int lg   = lane >> 4, ln = lane & 15;
    const int row0 = blockIdx.x * 64;

    // ---- prologue: weights for L0 (small file) + L1 (full file), stage x ----
    h8 w0[2][4];
#pragma unroll
    for (int s = 0; s < 2; ++s)
#pragma unroll
        for (int nf = 0; nf < 4; ++nf)
            w0[s][nf] = *bfrag_ptr(wf + OFF_L0, s, wid, nf, lane);

    h8 w[8][4];
#pragma unroll
    for (int ks = 0; ks < 8; ++ks)
#pragma unroll
        for (int nf = 0; nf < 4; ++nf)
            w[ks][nf] = *bfrag_ptr(wf + OFF_L1, ks, wid, nf, lane);

    h8 wx[2][4];   // L5 x-part / Wout scratch weights

    for (int idx = tid; idx < 64 * 64; idx += 256) {
        int r = idx >> 6, c = idx & 63;
        float v = (c < 63) ? x[(size_t)(row0 + r) * 90 + c] : 0.f;
        xb[r >> 5][r & 31][c] = (_Float16)v;
    }

    float bv0[4], bv1[4], bv2[4], bv3[4], bv4[4], bv5[4], bv6[4], bv7[4];
#pragma unroll
    for (int nf = 0; nf < 4; ++nf) bv0[nf] = b0[wid * 64 + nf * 16 + ln];

    f4 accA[2][4], accB[2][4];
    __syncthreads();

    // ---- pipeline: segA(L)=mainA||epiB(L-1), segB(L)=mainB||epiA(L)||stream W(L+1)
    // L0 (K=64, A from xb; W(L1) already streaming from prologue)
    segment<2, 2, 1, false, false, false, 0>(hb[0], xb[0], hb[1], w0, wx, wf, wf, accA, accB, bv0, wid, lane);
    segment<2, 2, 1, false, true,  false, 0>(hb[1], xb[1], hb[0], w0, wx, wf, wf, accB, accA, bv0, wid, lane);

#pragma unroll
    for (int nf = 0; nf < 4; ++nf) bv1[nf] = b1[wid * 64 + nf * 16 + ln];
    segment<8, 8, 0, false, true, false, 0>(hb[0], xb[0], hb[1], w, wx, wf, wf, accA, accB, bv0, wid, lane);
    segment<8, 8, 0, false, true, true,  0>(hb[1], xb[1], hb[0], w, wx, wf + OFF_L2, wf, accB, accA, bv1, wid, lane);

#pragma unroll
    for (int nf = 0; nf < 4; ++nf) bv2[nf] = b2[wid * 64 + nf * 16 + ln];
    segment<8, 8, 0, false, true, false, 0>(hb[0], xb[0], hb[1], w, wx, wf, wf, accA, accB, bv1, wid, lane);
    segment<8, 8, 0, false, true, true,  0>(hb[1], xb[1], hb[0], w, wx, wf + OFF_L3, wf, accB, accA, bv2, wid, lane);

#pragma unroll
    for (int nf = 0; nf < 4; ++nf) bv3[nf] = b3[wid * 64 + nf * 16 + ln];
    segment<8, 8, 0, false, true, false, 0>(hb[0], xb[0], hb[1], w, wx, wf, wf, accA, accB, bv2, wid, lane);
    segment<8, 8, 0, false, true, true,  0>(hb[1], xb[1], hb[0], w, wx, wf + OFF_L4, wf, accB, accA, bv3, wid, lane);

#pragma unroll
    for (int nf = 0; nf < 4; ++nf) bv4[nf] = b4[wid * 64 + nf * 16 + ln];
    segment<8, 8, 0, false, true, false, 0>(hb[0], xb[0], hb[1], w, wx, wf, wf, accA, accB, bv3, wid, lane);
    segment<8, 8, 0, false, true, true,  0>(hb[1], xb[1], hb[0], w, wx, wf + OFF_L5, wf, accB, accA, bv4, wid, lane);

    // L5: 8 ks from h + 2 ks from x (skip concat), wx streamed per segment
#pragma unroll
    for (int nf = 0; nf < 4; ++nf) bv5[nf] = b5[wid * 64 + nf * 16 + ln];
    segment<8, 8, 0, true, true, false, 1>(hb[0], xb[0], hb[1], w, wx, wf, wf + OFF_L5, accA, accB, bv4, wid, lane);
    segment<8, 8, 0, true, true, true,  1>(hb[1], xb[1], hb[0], w, wx, wf + OFF_L6, wf + OFF_L5, accB, accA, bv5, wid, lane);

#pragma unroll
    for (int nf = 0; nf < 4; ++nf) bv6[nf] = b6[wid * 64 + nf * 16 + ln];
    segment<8, 8, 0, false, true, false, 0>(hb[0], xb[0], hb[1], w, wx, wf, wf, accA, accB, bv5, wid, lane);
    segment<8, 8, 0, false, true, true,  0>(hb[1], xb[1], hb[0], w, wx, wf + OFF_L7, wf, accB, accA, bv6, wid, lane);

    // L7: segB loads Wout into wx (w must survive for mainB's own use)
#pragma unroll
    for (int nf = 0; nf < 4; ++nf) bv7[nf] = b7[wid * 64 + nf * 16 + ln];
    segment<8, 8, 0, false, true, false, 0>(hb[0], xb[0], hb[1], w, wx, wf, wf, accA, accB, bv6, wid, lane);
    segment<8, 8, 0, false, true, false, 2>(hb[1], xb[1], hb[0], w, wx, wf, wf + OFF_OUT, accB, accA, bv7, wid, lane);

    // ---- final1: epiB(L7) (all waves) || outA (waves 0,1) ----
#pragma unroll
    for (int j = 0; j < 8; ++j) {
        const int mf_ = j & 1, nf_ = j >> 1;
        float b_ = bv7[nf_];
#pragma unroll
        for (int i = 0; i < 4; ++i) {
            float v_ = accB[mf_][nf_][i] + b_;
            v_ = fmaxf(v_, 0.f);
            hb[1][mf_ * 16 + lg * 4 + i][wid * 64 + nf_ * 16 + ln] = (_Float16)v_;
        }
    }
    if (wid < 2) {
        f4 oacc;
#pragma unroll
        for (int i = 0; i < 4; ++i) oacc[i] = 0.f;
#pragma unroll
        for (int ks = 0; ks < 8; ++ks) {
            h8 afr = *(const h8*)&hb[0][(wid & 1) * 16 + ln][ks * 32 + lg * 8];
            oacc = __builtin_amdgcn_mfma_f32_16x16x32_f16(afr, wx[ks >> 2][ks & 3], oacc, 0, 0, 0);
        }
        if (ln < 4) {
            float bo = bout[ln];
#pragma unroll
            for (int i = 0; i < 4; ++i) {
                int r = row0 + (wid & 1) * 16 + lg * 4 + i;
                out[(size_t)r * 4 + ln] = oacc[i] + bo;
            }
        }
    }
    __syncthreads();

    // ---- final2: outB (waves 2,3) ----
    if (wid >= 2) {
        f4 oacc;
#pragma unroll
        for (int i = 0; i < 4; ++i) oacc[i] = 0.f;
#pragma unroll
        for (int ks = 0; ks < 8; ++ks) {
            h8 afr = *(const h8*)&hb[1][(wid & 1) * 16 + ln][ks * 32 + lg * 8];
            oacc = __builtin_amdgcn_mfma_f32_16x16x32_f16(afr, wx[ks >> 2][ks & 3], oacc, 0, 0, 0);
        }
        if (ln < 4) {
            float bo = bout[ln];
#pragma unroll
            for (int i = 0; i < 4; ++i) {
                int r = row0 + 32 + (wid & 1) * 16 + lg * 4 + i;
                out[(size_t)r * 4 + ln] = oacc[i] + bo;
            }
        }
    }
}

extern "C" void kernel_launch(void* const* d_in, const int* in_sizes, int n_in,
                              void* d_out, int out_size, void* d_ws, size_t ws_size,
                              hipStream_t stream)
{
    const float* x = (const float*)d_in[0];
    const float* W[9];
    const float* b[9];
    for (int i = 0; i < 8; ++i) {
        W[i] = (const float*)d_in[1 + 2 * i];
        b[i] = (const float*)d_in[2 + 2 * i];
    }
    W[8] = (const float*)d_in[17];   // Wout
    b[8] = (const float*)d_in[18];   // bout

    _Float16* wf = (_Float16*)d_ws;

    nerf_prep<<<(TOT_GROUPS + 255) / 256, 256, 0, stream>>>(
        W[0], W[1], W[2], W[3], W[4], W[5], W[6], W[7], W[8], wf);

    nerf_fused<<<262144 / 64, 256, 0, stream>>>(
        x, b[0], b[1], b[2], b[3], b[4], b[5], b[6], b[7], b[8], wf,
        (float*)d_out);
}